// Round 1
// baseline (126.593 us; speedup 1.0000x reference)
//
#include <hip/hip_runtime.h>

typedef __bf16 bf16x8 __attribute__((ext_vector_type(8)));
typedef float f32x4 __attribute__((ext_vector_type(4)));

#define DEV static __device__ __forceinline__

DEV unsigned short f2bf(float f) {
    union { float f; unsigned u; } c; c.f = f;
    unsigned u = c.u;
    return (unsigned short)((u + 0x7FFFu + ((u >> 16) & 1u)) >> 16);
}
DEV float bf2f(unsigned short h) {
    union { unsigned u; float f; } c; c.u = ((unsigned)h) << 16;
    return c.f;
}

DEV f32x4 mfma16(bf16x8 a, bf16x8 b, f32x4 c) {
    return __builtin_amdgcn_mfma_f32_16x16x32_bf16(a, b, c, 0, 0, 0);
}

#define GLOAD16(gp, lp)                                                        \
    __builtin_amdgcn_global_load_lds(                                          \
        (const __attribute__((address_space(1))) unsigned int*)(gp),           \
        (__attribute__((address_space(3))) unsigned int*)(lp), 16, 0, 0)

// ---------------------------------------------------------------- LN -> y bf16
__global__ __launch_bounds__(256) void ln_kernel(const float* __restrict__ x,
                                                 const float* __restrict__ lnsc,
                                                 unsigned short* __restrict__ y) {
    const int t = threadIdx.x;
    const int token = blockIdx.x * 4 + (t >> 6);
    const int lane = t & 63;
    const float4* xp = (const float4*)(x + (size_t)token * 512 + lane * 8);
    float4 v0 = xp[0], v1 = xp[1];
    float s = v0.x + v0.y + v0.z + v0.w + v1.x + v1.y + v1.z + v1.w;
    float s2 = v0.x * v0.x + v0.y * v0.y + v0.z * v0.z + v0.w * v0.w +
               v1.x * v1.x + v1.y * v1.y + v1.z * v1.z + v1.w * v1.w;
#pragma unroll
    for (int off = 1; off < 64; off <<= 1) {
        s += __shfl_xor(s, off);
        s2 += __shfl_xor(s2, off);
    }
    const float mean = s * (1.0f / 512.0f);
    const float var = s2 * (1.0f / 512.0f) - mean * mean;
    const float rstd = rsqrtf(var + 1e-5f);
    const float4* sp = (const float4*)(lnsc + lane * 8);
    float4 sc0 = sp[0], sc1 = sp[1];
    float o[8];
    o[0] = (v0.x - mean) * rstd * sc0.x;
    o[1] = (v0.y - mean) * rstd * sc0.y;
    o[2] = (v0.z - mean) * rstd * sc0.z;
    o[3] = (v0.w - mean) * rstd * sc0.w;
    o[4] = (v1.x - mean) * rstd * sc1.x;
    o[5] = (v1.y - mean) * rstd * sc1.y;
    o[6] = (v1.z - mean) * rstd * sc1.z;
    o[7] = (v1.w - mean) * rstd * sc1.w;
    unsigned p0 = f2bf(o[0]) | ((unsigned)f2bf(o[1]) << 16);
    unsigned p1 = f2bf(o[2]) | ((unsigned)f2bf(o[3]) << 16);
    unsigned p2 = f2bf(o[4]) | ((unsigned)f2bf(o[5]) << 16);
    unsigned p3 = f2bf(o[6]) | ((unsigned)f2bf(o[7]) << 16);
    uint4 pk = make_uint4(p0, p1, p2, p3);
    *(uint4*)(y + (size_t)token * 512 + lane * 8) = pk;
}

// ----------------------------------------- weights: fp32 -> bf16, transposed
__global__ __launch_bounds__(256) void conv_weights(const float* __restrict__ wqkv,
                                                    const float* __restrict__ wout,
                                                    unsigned short* __restrict__ wqkvt,
                                                    unsigned short* __restrict__ woutt) {
    const int i = blockIdx.x * 256 + threadIdx.x;
    if (i < 512 * 1536) {
        int f = i >> 9, c = i & 511;
        wqkvt[i] = f2bf(wqkv[(size_t)c * 1536 + f]);
    } else {
        int j = i - 512 * 1536;
        if (j < 512 * 512) {
            int n = j >> 9, k = j & 511;
            woutt[j] = f2bf(wout[(size_t)k * 512 + n]);
        }
    }
}

// ------------------------------------------------------- GEMM C = A * Bt^T
// A: [M,K] bf16 row-major, Bt: [N,K] bf16 row-major. 128x128 tile, BK=64,
// 4 waves each 64x64. XOR-swizzled LDS via pre-swizzled global source.
template <int NCOLS, bool OUT_BF16, bool BIAS>
__global__ __launch_bounds__(256) void gemm_bt(const unsigned short* __restrict__ A,
                                               const unsigned short* __restrict__ Bt,
                                               void* __restrict__ Cout,
                                               const float* __restrict__ bias,
                                               int M, int K) {
    __shared__ unsigned short As[128 * 64];
    __shared__ unsigned short Bs[128 * 64];
    const int t = threadIdx.x;
    const int w = t >> 6, lane = t & 63;
    const int g = lane >> 4, l15 = lane & 15;
    const int wr = w >> 1, wc = w & 1;
    const int bR = blockIdx.y, bC = blockIdx.x;
    f32x4 acc[4][4] = {};
    const size_t ldAb = (size_t)K * 2;
    const char* Ag = (const char*)A + (size_t)bR * 128 * ldAb;
    const char* Bg = (const char*)Bt + (size_t)bC * 128 * ldAb;

    for (int kt = 0; kt < K; kt += 64) {
        __syncthreads();
#pragma unroll
        for (int i = 0; i < 4; i++) {
            int o = i * 4096 + t * 16;
            int row = o >> 7, bo = o & 127;
            int kb = bo ^ ((row & 7) << 4);
            GLOAD16(Ag + (size_t)row * ldAb + (size_t)kt * 2 + kb, (char*)As + o);
            GLOAD16(Bg + (size_t)row * ldAb + (size_t)kt * 2 + kb, (char*)Bs + o);
        }
        asm volatile("s_waitcnt vmcnt(0)" ::: "memory");
        __syncthreads();
#pragma unroll
        for (int kk = 0; kk < 64; kk += 32) {
            bf16x8 a[4], bb[4];
#pragma unroll
            for (int m = 0; m < 4; m++) {
                int row = wr * 64 + m * 16 + l15;
                int kb = ((kk + g * 8) * 2) ^ ((row & 7) << 4);
                a[m] = *(const bf16x8*)((const char*)As + row * 128 + kb);
            }
#pragma unroll
            for (int n = 0; n < 4; n++) {
                int row = wc * 64 + n * 16 + l15;
                int kb = ((kk + g * 8) * 2) ^ ((row & 7) << 4);
                bb[n] = *(const bf16x8*)((const char*)Bs + row * 128 + kb);
            }
#pragma unroll
            for (int m = 0; m < 4; m++)
#pragma unroll
                for (int n = 0; n < 4; n++)
                    acc[m][n] = mfma16(a[m], bb[n], acc[m][n]);
        }
    }
    const int rbase = bR * 128 + wr * 64;
    const int cbase = bC * 128 + wc * 64;
#pragma unroll
    for (int m = 0; m < 4; m++)
#pragma unroll
        for (int n = 0; n < 4; n++)
#pragma unroll
            for (int r = 0; r < 4; r++) {
                int row = rbase + m * 16 + g * 4 + r;
                int col = cbase + n * 16 + l15;
                float v = acc[m][n][r];
                if constexpr (OUT_BF16) {
                    ((unsigned short*)Cout)[(size_t)row * NCOLS + col] = f2bf(v);
                } else {
                    float bv = BIAS ? bias[col] : 0.0f;
                    ((float*)Cout)[(size_t)row * NCOLS + col] = v + bv;
                }
            }
}

// -------------------------------------- in-place token-axis l2norm of q and k
__global__ __launch_bounds__(256) void l2norm_qk(unsigned short* __restrict__ qkv) {
    const int b = blockIdx.x >> 4, fg = blockIdx.x & 15;
    const int t = threadIdx.x;
    const int col = fg * 64 + (t & 63);  // f in [0,1024): q then k
    const int rq = t >> 6;
    const size_t base = (size_t)b * 1024 * 1536 + col;
    float ss = 0.0f;
    for (int i = 0; i < 256; i++) {
        int r = rq + i * 4;
        float v = bf2f(qkv[base + (size_t)r * 1536]);
        ss += v * v;
    }
    __shared__ float red[4][64];
    __shared__ float rn[64];
    red[rq][t & 63] = ss;
    __syncthreads();
    if (t < 64) {
        float tot = red[0][t] + red[1][t] + red[2][t] + red[3][t];
        rn[t] = 1.0f / fmaxf(sqrtf(tot), 1e-12f);
    }
    __syncthreads();
    const float sc = rn[t & 63];
    for (int i = 0; i < 256; i++) {
        int r = rq + i * 4;
        size_t idx = base + (size_t)r * 1536;
        qkv[idx] = f2bf(bf2f(qkv[idx]) * sc);
    }
}

// ------------------------------------------- V transpose: vt[bh, d, n] layout
__global__ __launch_bounds__(256) void v_transpose(const unsigned short* __restrict__ qkv,
                                                   unsigned short* __restrict__ vt) {
    const int nt = blockIdx.x, bh = blockIdx.y;
    const int b = bh >> 3, h = bh & 7;
    __shared__ unsigned short tile[64][68];
    const int t = threadIdx.x;
#pragma unroll
    for (int j = 0; j < 16; j++) {
        int idx = t + j * 256;
        int nl = idx >> 6, d = idx & 63;
        tile[d][nl] = qkv[((size_t)b * 1024 + nt * 64 + nl) * 1536 + 1024 + h * 64 + d];
    }
    __syncthreads();
#pragma unroll
    for (int j = 0; j < 16; j++) {
        int idx = t + j * 256;
        int d = idx >> 6, nl = idx & 63;
        vt[((size_t)bh * 64 + d) * 1024 + nt * 64 + nl] = tile[d][nl];
    }
}

// ------------------------------------------------------- flash-ish attention
// grid: x = q-tile (16), y = bh (64). 4 waves, each 16 q-rows. KVBLK=64.
// No max-subtraction (sim range is tiny): accumulate exp directly.
__global__ __launch_bounds__(256) void attn_kernel(const unsigned short* __restrict__ qkv,
                                                   const unsigned short* __restrict__ vt,
                                                   unsigned short* __restrict__ attnout) {
    __shared__ unsigned short Qs[64 * 64];
    __shared__ unsigned short Ks[64 * 64];
    __shared__ unsigned short Vs[64 * 64];
    __shared__ unsigned short Ps[4][16 * 72];
    const int t = threadIdx.x;
    const int w = t >> 6, lane = t & 63;
    const int g = lane >> 4, l15 = lane & 15;
    const int qt = blockIdx.x, bh = blockIdx.y;
    const int b = bh >> 3, h = bh & 7;
    const size_t qrow0 = (size_t)b * 1024 + qt * 64;
    const char* qg = (const char*)qkv;

    // stage Q once (rows: token, cols: d) — swizzled source
#pragma unroll
    for (int i = 0; i < 2; i++) {
        int o = i * 4096 + t * 16;
        int row = o >> 7, bo = o & 127;
        int kb = bo ^ ((row & 7) << 4);
        GLOAD16(qg + (qrow0 + row) * 3072 + h * 128 + kb, (char*)Qs + o);
    }

    f32x4 accO[4] = {};
    float prs[4] = {0.f, 0.f, 0.f, 0.f};

    for (int kt = 0; kt < 1024; kt += 64) {
        __syncthreads();
#pragma unroll
        for (int i = 0; i < 2; i++) {
            int o = i * 4096 + t * 16;
            int row = o >> 7, bo = o & 127;
            int kb = bo ^ ((row & 7) << 4);
            GLOAD16(qg + ((size_t)b * 1024 + kt + row) * 3072 + 1024 + h * 128 + kb,
                    (char*)Ks + o);
            GLOAD16((const char*)vt + ((size_t)bh * 64 + row) * 2048 + (size_t)kt * 2 + kb,
                    (char*)Vs + o);
        }
        asm volatile("s_waitcnt vmcnt(0)" ::: "memory");
        __syncthreads();

        // S = Q K^T  (16q x 64kv per wave)
        f32x4 s[4] = {};
#pragma unroll
        for (int kk = 0; kk < 64; kk += 32) {
            int qrow = w * 16 + l15;
            int kbq = ((kk + g * 8) * 2) ^ ((qrow & 7) << 4);
            bf16x8 aq = *(const bf16x8*)((const char*)Qs + qrow * 128 + kbq);
#pragma unroll
            for (int n = 0; n < 4; n++) {
                int krow = n * 16 + l15;
                int kbk = ((kk + g * 8) * 2) ^ ((krow & 7) << 4);
                bf16x8 bk = *(const bf16x8*)((const char*)Ks + krow * 128 + kbk);
                s[n] = mfma16(aq, bk, s[n]);
            }
        }
        // P = exp(10*S); accumulate row sums; write P to per-wave LDS
#pragma unroll
        for (int n = 0; n < 4; n++)
#pragma unroll
            for (int r = 0; r < 4; r++) {
                float p = __expf(10.0f * s[n][r]);
                prs[r] += p;
                Ps[w][(g * 4 + r) * 72 + n * 16 + l15] = f2bf(p);
            }
        // PV: O += P * V   (A = P [16q x kv], B = Vt [d x kv])
#pragma unroll
        for (int kt2 = 0; kt2 < 64; kt2 += 32) {
            bf16x8 ap = *(const bf16x8*)((const char*)(&Ps[w][0]) + (size_t)l15 * 144 +
                                         (kt2 + g * 8) * 2);
#pragma unroll
            for (int n = 0; n < 4; n++) {
                int vrow = n * 16 + l15;
                int kbv = ((kt2 + g * 8) * 2) ^ ((vrow & 7) << 4);
                bf16x8 bv = *(const bf16x8*)((const char*)Vs + vrow * 128 + kbv);
                accO[n] = mfma16(ap, bv, accO[n]);
            }
        }
    }
    // reduce row sums across the 16 kv-column lanes
#pragma unroll
    for (int r = 0; r < 4; r++)
#pragma unroll
        for (int off = 1; off < 16; off <<= 1) prs[r] += __shfl_xor(prs[r], off);
    // write O = accO / rowsum, bf16, [token, h*64+d]
#pragma unroll
    for (int n = 0; n < 4; n++)
#pragma unroll
        for (int r = 0; r < 4; r++) {
            float v = accO[n][r] / prs[r];
            attnout[(qrow0 + w * 16 + g * 4 + r) * 512 + h * 64 + n * 16 + l15] = f2bf(v);
        }
}

// ---------------------------------------------------------------- launcher
extern "C" void kernel_launch(void* const* d_in, const int* in_sizes, int n_in,
                              void* d_out, int out_size, void* d_ws, size_t ws_size,
                              hipStream_t stream) {
    const float* x = (const float*)d_in[0];
    const float* ln_scale = (const float*)d_in[1];
    const float* w_qkv = (const float*)d_in[2];
    const float* w_out = (const float*)d_in[3];
    const float* b_out = (const float*)d_in[4];
    float* out = (float*)d_out;

    char* ws = (char*)d_ws;
    // layout (bytes):
    unsigned short* y = (unsigned short*)(ws + 0);                  // 8 MB (reused as attnout)
    unsigned short* wqkvt = (unsigned short*)(ws + 8388608);        // 1.5 MB
    unsigned short* woutt = (unsigned short*)(ws + 9961472);        // 0.5 MB
    unsigned short* qkv = (unsigned short*)(ws + 10485760);         // 24 MB
    unsigned short* vt = (unsigned short*)(ws + 35651584);          // 8 MB
    unsigned short* attnout = (unsigned short*)(ws + 0);            // overlaps y (dead)

    ln_kernel<<<2048, 256, 0, stream>>>(x, ln_scale, y);
    conv_weights<<<4096, 256, 0, stream>>>(w_qkv, w_out, wqkvt, woutt);
    gemm_bt<1536, true, false><<<dim3(12, 64), 256, 0, stream>>>(y, wqkvt, qkv, nullptr,
                                                                 8192, 512);
    l2norm_qk<<<128, 256, 0, stream>>>(qkv);
    v_transpose<<<dim3(16, 64), 256, 0, stream>>>(qkv, vt);
    attn_kernel<<<dim3(16, 64), 256, 0, stream>>>(qkv, vt, attnout);
    gemm_bt<512, false, true><<<dim3(4, 64), 256, 0, stream>>>(attnout, woutt, out, b_out,
                                                               8192, 512);
}

// Round 2
// 90.415 us; speedup vs baseline: 1.4001x; 1.4001x over previous
//
#include <hip/hip_runtime.h>

typedef __bf16 bf16x8 __attribute__((ext_vector_type(8)));
typedef float f32x4 __attribute__((ext_vector_type(4)));

#define DEV static __device__ __forceinline__

DEV unsigned short f2bf(float f) {
    union { __bf16 h; unsigned short s; } c; c.h = (__bf16)f; return c.s;
}
DEV float bf2f(unsigned short h) {
    union { unsigned u; float f; } c; c.u = ((unsigned)h) << 16; return c.f;
}
DEV unsigned packbf2(float a, float b) {
    union { __bf16 h[2]; unsigned u; } c;
    c.h[0] = (__bf16)a; c.h[1] = (__bf16)b; return c.u;
}

DEV f32x4 mfma16(bf16x8 a, bf16x8 b, f32x4 c) {
    return __builtin_amdgcn_mfma_f32_16x16x32_bf16(a, b, c, 0, 0, 0);
}

#define GLOAD16(gp, lp)                                                        \
    __builtin_amdgcn_global_load_lds(                                          \
        (const __attribute__((address_space(1))) unsigned int*)(gp),           \
        (__attribute__((address_space(3))) unsigned int*)(lp), 16, 0, 0)

// ---------------------------------------------------------------- LN -> y bf16
__global__ __launch_bounds__(256) void ln_kernel(const float* __restrict__ x,
                                                 const float* __restrict__ lnsc,
                                                 unsigned short* __restrict__ y,
                                                 float* __restrict__ ssq) {
    const int t = threadIdx.x;
    if (blockIdx.x < 32) ssq[(blockIdx.x << 8) | t] = 0.0f;  // zero 8192 norm accumulators
    const int token = blockIdx.x * 4 + (t >> 6);
    const int lane = t & 63;
    const float4* xp = (const float4*)(x + (size_t)token * 512 + lane * 8);
    float4 v0 = xp[0], v1 = xp[1];
    float s = v0.x + v0.y + v0.z + v0.w + v1.x + v1.y + v1.z + v1.w;
    float s2 = v0.x * v0.x + v0.y * v0.y + v0.z * v0.z + v0.w * v0.w +
               v1.x * v1.x + v1.y * v1.y + v1.z * v1.z + v1.w * v1.w;
#pragma unroll
    for (int off = 1; off < 64; off <<= 1) {
        s += __shfl_xor(s, off);
        s2 += __shfl_xor(s2, off);
    }
    const float mean = s * (1.0f / 512.0f);
    const float var = s2 * (1.0f / 512.0f) - mean * mean;
    const float rstd = rsqrtf(var + 1e-5f);
    const float4* sp = (const float4*)(lnsc + lane * 8);
    float4 sc0 = sp[0], sc1 = sp[1];
    union { __bf16 h[8]; uint4 v; } pk;
    pk.h[0] = (__bf16)((v0.x - mean) * rstd * sc0.x);
    pk.h[1] = (__bf16)((v0.y - mean) * rstd * sc0.y);
    pk.h[2] = (__bf16)((v0.z - mean) * rstd * sc0.z);
    pk.h[3] = (__bf16)((v0.w - mean) * rstd * sc0.w);
    pk.h[4] = (__bf16)((v1.x - mean) * rstd * sc1.x);
    pk.h[5] = (__bf16)((v1.y - mean) * rstd * sc1.y);
    pk.h[6] = (__bf16)((v1.z - mean) * rstd * sc1.z);
    pk.h[7] = (__bf16)((v1.w - mean) * rstd * sc1.w);
    *(uint4*)(y + (size_t)token * 512 + lane * 8) = pk.v;
}

// ----------------------------------------- weights: fp32 -> bf16, transposed
__global__ __launch_bounds__(256) void conv_weights(const float* __restrict__ wqkv,
                                                    const float* __restrict__ wout,
                                                    unsigned short* __restrict__ wqkvt,
                                                    unsigned short* __restrict__ woutt) {
    const int i = blockIdx.x * 256 + threadIdx.x;
    if (i < 512 * 1536) {
        int f = i >> 9, c = i & 511;
        wqkvt[i] = f2bf(wqkv[(size_t)c * 1536 + f]);
    } else {
        int j = i - 512 * 1536;
        if (j < 512 * 512) {
            int n = j >> 9, k = j & 511;
            woutt[j] = f2bf(wout[(size_t)k * 512 + n]);
        }
    }
}

// ------------------------------------------------------- GEMM C = A * Bt^T
// A: [M,K] bf16 row-major, Bt: [N,K] bf16 row-major. Block tile 2WM x 2WN,
// BK=64, 4 waves (2x2), each WM x WN. XOR-swizzled LDS via pre-swizzled src.
// SSQ: accumulate per-column sum-of-squares (cols < 1024) for l2norm folding.
template <int WM, int WN, int NCOLS, bool OUT_BF16, bool BIAS, bool SSQ>
__global__ __launch_bounds__(256) void gemm_bt(const unsigned short* __restrict__ A,
                                               const unsigned short* __restrict__ Bt,
                                               void* __restrict__ Cout,
                                               const float* __restrict__ bias,
                                               float* __restrict__ ssq,
                                               int M, int K) {
    constexpr int BM = 2 * WM, BN = 2 * WN;
    __shared__ unsigned short As[BM * 64];
    __shared__ unsigned short Bs[BN * 64];
    const int t = threadIdx.x;
    const int w = t >> 6, lane = t & 63;
    const int g = lane >> 4, l15 = lane & 15;
    const int wr = w >> 1, wc = w & 1;
    const int bR = blockIdx.y, bC = blockIdx.x;
    f32x4 acc[WM / 16][WN / 16] = {};
    const size_t ldb = (size_t)K * 2;
    const char* Ag = (const char*)A + (size_t)bR * BM * ldb;
    const char* Bg = (const char*)Bt + (size_t)bC * BN * ldb;

    for (int kt = 0; kt < K; kt += 64) {
        __syncthreads();
#pragma unroll
        for (int i = 0; i < WM / 16; i++) {
            int o = i * 4096 + t * 16;
            int row = o >> 7, kb = (o & 127) ^ ((row & 7) << 4);
            GLOAD16(Ag + (size_t)row * ldb + (size_t)kt * 2 + kb, (char*)As + o);
        }
#pragma unroll
        for (int i = 0; i < WN / 16; i++) {
            int o = i * 4096 + t * 16;
            int row = o >> 7, kb = (o & 127) ^ ((row & 7) << 4);
            GLOAD16(Bg + (size_t)row * ldb + (size_t)kt * 2 + kb, (char*)Bs + o);
        }
        asm volatile("s_waitcnt vmcnt(0)" ::: "memory");
        __syncthreads();
#pragma unroll
        for (int kk = 0; kk < 64; kk += 32) {
            bf16x8 a[WM / 16], bb[WN / 16];
#pragma unroll
            for (int m = 0; m < WM / 16; m++) {
                int row = wr * WM + m * 16 + l15;
                int kb = ((kk + g * 8) * 2) ^ ((row & 7) << 4);
                a[m] = *(const bf16x8*)((const char*)As + row * 128 + kb);
            }
#pragma unroll
            for (int n = 0; n < WN / 16; n++) {
                int row = wc * WN + n * 16 + l15;
                int kb = ((kk + g * 8) * 2) ^ ((row & 7) << 4);
                bb[n] = *(const bf16x8*)((const char*)Bs + row * 128 + kb);
            }
#pragma unroll
            for (int m = 0; m < WM / 16; m++)
#pragma unroll
                for (int n = 0; n < WN / 16; n++)
                    acc[m][n] = mfma16(a[m], bb[n], acc[m][n]);
        }
    }
    const int rbase = bR * BM + wr * WM;
    const int cbase = bC * BN + wc * WN;
#pragma unroll
    for (int m = 0; m < WM / 16; m++)
#pragma unroll
        for (int n = 0; n < WN / 16; n++)
#pragma unroll
            for (int r = 0; r < 4; r++) {
                int row = rbase + m * 16 + g * 4 + r;
                int col = cbase + n * 16 + l15;
                float v = acc[m][n][r];
                if constexpr (OUT_BF16)
                    ((unsigned short*)Cout)[(size_t)row * NCOLS + col] = f2bf(v);
                else
                    ((float*)Cout)[(size_t)row * NCOLS + col] = v + (BIAS ? bias[col] : 0.f);
            }
    if constexpr (SSQ) {
        if (bC < 8) {  // q,k columns only (cols < 1024)
            const int bb2 = bR >> 3;  // 8 row-blocks of 128 per batch (1024 tokens)
#pragma unroll
            for (int n = 0; n < WN / 16; n++) {
                float ps = 0.f;
#pragma unroll
                for (int m = 0; m < WM / 16; m++)
#pragma unroll
                    for (int r = 0; r < 4; r++) ps += acc[m][n][r] * acc[m][n][r];
                ps += __shfl_xor(ps, 16);
                ps += __shfl_xor(ps, 32);
                if (g == 0)
                    atomicAdd(&ssq[bb2 * 1024 + cbase + n * 16 + l15], ps);
            }
        }
    }
}

// ---------------- V transpose to vt[bh][d][n] + fold l2norm scales into q
// scale(b,h,d) = 10*log2e / (max(|q_col|,eps) * max(|k_col|,eps))
__global__ __launch_bounds__(256) void vtrans_qscale(unsigned short* __restrict__ qkv,
                                                     unsigned short* __restrict__ vt,
                                                     const float* __restrict__ ssq) {
    const int nt = blockIdx.x, bh = blockIdx.y;
    const int b = bh >> 3, h = bh & 7;
    const int t = threadIdx.x;
    __shared__ unsigned short tile[64][68];
    __shared__ float sm[64];
#pragma unroll
    for (int j = 0; j < 16; j++) {
        int idx = t + j * 256;
        int nl = idx >> 6, d = idx & 63;
        tile[d][nl] = qkv[((size_t)b * 1024 + nt * 64 + nl) * 1536 + 1024 + h * 64 + d];
    }
    if (t < 64) {
        float nq = fmaxf(sqrtf(ssq[b * 1024 + h * 64 + t]), 1e-12f);
        float nk = fmaxf(sqrtf(ssq[b * 1024 + 512 + h * 64 + t]), 1e-12f);
        sm[t] = 14.42695040888963f / (nq * nk);  // 10*log2(e) folded in
    }
    __syncthreads();
#pragma unroll
    for (int j = 0; j < 16; j++) {
        int idx = t + j * 256;
        int d = idx >> 6, nl = idx & 63;
        vt[((size_t)bh * 64 + d) * 1024 + nt * 64 + nl] = tile[d][nl];
    }
    // scale q in place: 16 channels per thread for 1 token
    const int tok = nt * 64 + (t >> 2), d0 = (t & 3) * 16;
    unsigned short* qp = qkv + ((size_t)b * 1024 + tok) * 1536 + h * 64 + d0;
#pragma unroll
    for (int half = 0; half < 2; half++) {
        uint4 v = *(const uint4*)(qp + half * 8);
        const unsigned* vv = (const unsigned*)&v;
        unsigned r[4];
#pragma unroll
        for (int j = 0; j < 4; j++) {
            int dd = d0 + half * 8 + j * 2;
            float f0 = bf2f((unsigned short)(vv[j] & 0xffffu));
            float f1 = bf2f((unsigned short)(vv[j] >> 16));
            r[j] = packbf2(f0 * sm[dd], f1 * sm[dd + 1]);
        }
        *(uint4*)(qp + half * 8) = *(uint4*)r;
    }
}

// ------------------------------------------------------- flash-ish attention
// grid: x = q-tile of 128 (8 per batch), y = bh (64). 4 waves, each 32 q-rows.
// Q in registers (pre-scaled by 10*log2e/(nq*nk)); K raw; KVBLK=64, dbuf K/V.
// Swapped QK^T (mfma(K,Q)) -> lane owns P row slice -> cvt_pk pack -> LDS P.
__global__ __launch_bounds__(256) void attn_kernel(const unsigned short* __restrict__ qkv,
                                                   const unsigned short* __restrict__ vt,
                                                   unsigned short* __restrict__ attnout) {
    __shared__ unsigned short Ks[2][4096];
    __shared__ unsigned short Vs[2][4096];
    __shared__ unsigned short Ps[4][2048];  // per wave: 32 q x 64 kv, swizzled
    const int t = threadIdx.x, w = t >> 6, lane = t & 63;
    const int g = lane >> 4, l15 = lane & 15;
    const int qt = blockIdx.x, bh = blockIdx.y;
    const int b = bh >> 3, h = bh & 7;
    const size_t qrow0 = (size_t)b * 1024 + qt * 128;
    const char* qg = (const char*)qkv;
    const char* vg = (const char*)vt;

    // Q fragments in registers: q row = qrow0 + w*32 + qb*16 + l15, d = c*32+g*8..
    bf16x8 qf[2][2];
#pragma unroll
    for (int qb = 0; qb < 2; qb++)
#pragma unroll
        for (int c = 0; c < 2; c++)
            qf[qb][c] = *(const bf16x8*)(qkv + (qrow0 + w * 32 + qb * 16 + l15) * 1536 +
                                         h * 64 + c * 32 + g * 8);

    f32x4 accO[2][4] = {};
    float prs[2] = {0.f, 0.f};

#define ASTAGE(buf, tt_)                                                            \
    {                                                                               \
        const int kt_ = (tt_) * 64;                                                 \
        _Pragma("unroll") for (int i = 0; i < 2; i++) {                             \
            int o = i * 4096 + t * 16;                                              \
            int row = o >> 7, kb = (o & 127) ^ ((row & 7) << 4);                    \
            GLOAD16(qg + ((size_t)b * 1024 + kt_ + row) * 3072 + 1024 + h * 128 + kb, \
                    (char*)Ks[buf] + o);                                            \
            GLOAD16(vg + ((size_t)bh * 64 + row) * 2048 + (size_t)kt_ * 2 + kb,     \
                    (char*)Vs[buf] + o);                                            \
        }                                                                           \
    }

    ASTAGE(0, 0)
    for (int tt = 0; tt < 16; ++tt) {
        const int cur = tt & 1;
        if (tt < 15) {
            ASTAGE(cur ^ 1, tt + 1)
            asm volatile("s_waitcnt vmcnt(4)" ::: "memory");
        } else {
            asm volatile("s_waitcnt vmcnt(0)" ::: "memory");
        }
        __builtin_amdgcn_s_barrier();

        // S^T = K Q^T : s[qb][n], lane holds q=l15, kv = n*16 + g*4 + r
        f32x4 s[2][4] = {};
#pragma unroll
        for (int c = 0; c < 2; c++) {
            bf16x8 bk[4];
#pragma unroll
            for (int n = 0; n < 4; n++) {
                int krow = n * 16 + l15;
                int kb = ((c * 32 + g * 8) * 2) ^ ((krow & 7) << 4);
                bk[n] = *(const bf16x8*)((const char*)Ks[cur] + krow * 128 + kb);
            }
#pragma unroll
            for (int qb = 0; qb < 2; qb++)
#pragma unroll
                for (int n = 0; n < 4; n++)
                    s[qb][n] = mfma16(bk[n], qf[qb][c], s[qb][n]);
        }
        // P = 2^s ; rowsum; pack pairs -> Ps (XOR-swizzled, conflict-free b64)
#pragma unroll
        for (int qb = 0; qb < 2; qb++) {
            const int prow = qb * 16 + l15;
#pragma unroll
            for (int n = 0; n < 4; n++) {
                float p0 = __builtin_amdgcn_exp2f(s[qb][n][0]);
                float p1 = __builtin_amdgcn_exp2f(s[qb][n][1]);
                float p2 = __builtin_amdgcn_exp2f(s[qb][n][2]);
                float p3 = __builtin_amdgcn_exp2f(s[qb][n][3]);
                prs[qb] += (p0 + p1) + (p2 + p3);
                uint2 pk;
                pk.x = packbf2(p0, p1);
                pk.y = packbf2(p2, p3);
                int kb = ((n * 16 + g * 4) * 2) ^ ((prow & 7) << 4);
                *(uint2*)((char*)Ps[w] + prow * 128 + kb) = pk;
            }
        }
        // O += P * V  (A = P [q x kv], B = Vt [d x kv])
#pragma unroll
        for (int c2 = 0; c2 < 2; c2++) {
            bf16x8 bv[4];
#pragma unroll
            for (int n = 0; n < 4; n++) {
                int vrow = n * 16 + l15;
                int kb = ((c2 * 32 + g * 8) * 2) ^ ((vrow & 7) << 4);
                bv[n] = *(const bf16x8*)((const char*)Vs[cur] + vrow * 128 + kb);
            }
#pragma unroll
            for (int qb = 0; qb < 2; qb++) {
                const int prow = qb * 16 + l15;
                int kb = ((c2 * 32 + g * 8) * 2) ^ ((prow & 7) << 4);
                bf16x8 ap = *(const bf16x8*)((const char*)Ps[w] + prow * 128 + kb);
#pragma unroll
                for (int n = 0; n < 4; n++)
                    accO[qb][n] = mfma16(ap, bv[n], accO[qb][n]);
            }
        }
        __builtin_amdgcn_s_barrier();
    }
#undef ASTAGE
    // epilogue: rowsum reduce over g, redistribute, divide, store bf16
#pragma unroll
    for (int qb = 0; qb < 2; qb++) {
        float tot = prs[qb];
        tot += __shfl_xor(tot, 16);
        tot += __shfl_xor(tot, 32);
        float inv[4];
#pragma unroll
        for (int r = 0; r < 4; r++) inv[r] = 1.0f / __shfl(tot, g * 4 + r);
#pragma unroll
        for (int n = 0; n < 4; n++)
#pragma unroll
            for (int r = 0; r < 4; r++)
                attnout[(qrow0 + w * 32 + qb * 16 + g * 4 + r) * 512 + h * 64 + n * 16 +
                        l15] = f2bf(accO[qb][n][r] * inv[r]);
    }
}

// ---------------------------------------------------------------- launcher
extern "C" void kernel_launch(void* const* d_in, const int* in_sizes, int n_in,
                              void* d_out, int out_size, void* d_ws, size_t ws_size,
                              hipStream_t stream) {
    const float* x = (const float*)d_in[0];
    const float* ln_scale = (const float*)d_in[1];
    const float* w_qkv = (const float*)d_in[2];
    const float* w_out = (const float*)d_in[3];
    const float* b_out = (const float*)d_in[4];
    float* out = (float*)d_out;

    char* ws = (char*)d_ws;
    unsigned short* y = (unsigned short*)(ws + 0);            // 8 MB (reused as attnout)
    unsigned short* wqkvt = (unsigned short*)(ws + 8388608);  // 1.5 MB
    unsigned short* woutt = (unsigned short*)(ws + 9961472);  // 0.5 MB
    unsigned short* qkv = (unsigned short*)(ws + 10485760);   // 24 MB
    unsigned short* vt = (unsigned short*)(ws + 35651584);    // 8 MB
    float* ssq = (float*)(ws + 44040192);                     // 32 KB
    unsigned short* attnout = (unsigned short*)(ws + 0);      // overlaps y (dead)

    ln_kernel<<<2048, 256, 0, stream>>>(x, ln_scale, y, ssq);
    conv_weights<<<4096, 256, 0, stream>>>(w_qkv, w_out, wqkvt, woutt);
    gemm_bt<64, 64, 1536, true, false, true><<<dim3(12, 64), 256, 0, stream>>>(
        y, wqkvt, qkv, nullptr, ssq, 8192, 512);
    vtrans_qscale<<<dim3(16, 64), 256, 0, stream>>>(qkv, vt, ssq);
    attn_kernel<<<dim3(8, 64), 256, 0, stream>>>(qkv, vt, attnout);
    gemm_bt<32, 64, 512, false, true, false><<<dim3(4, 128), 256, 0, stream>>>(
        attnout, woutt, out, b_out, nullptr, 8192, 512);
}

// Round 3
// 81.535 us; speedup vs baseline: 1.5526x; 1.1089x over previous
//
#include <hip/hip_runtime.h>

typedef __bf16 bf16x8 __attribute__((ext_vector_type(8)));
typedef float f32x4 __attribute__((ext_vector_type(4)));

#define DEV static __device__ __forceinline__

DEV unsigned short f2bf(float f) {
    union { __bf16 h; unsigned short s; } c; c.h = (__bf16)f; return c.s;
}
DEV float bf2f(unsigned short h) {
    union { unsigned u; float f; } c; c.u = ((unsigned)h) << 16; return c.f;
}
DEV unsigned packbf2(float a, float b) {
    union { __bf16 h[2]; unsigned u; } c;
    c.h[0] = (__bf16)a; c.h[1] = (__bf16)b; return c.u;
}

DEV f32x4 mfma16(bf16x8 a, bf16x8 b, f32x4 c) {
    return __builtin_amdgcn_mfma_f32_16x16x32_bf16(a, b, c, 0, 0, 0);
}

#define GLOAD16(gp, lp)                                                        \
    __builtin_amdgcn_global_load_lds(                                          \
        (const __attribute__((address_space(1))) unsigned int*)(gp),           \
        (__attribute__((address_space(3))) unsigned int*)(lp), 16, 0, 0)

// --------------------------- LN -> y bf16 (blocks < 2048) + weight conversion
__global__ __launch_bounds__(256) void ln_conv_kernel(const float* __restrict__ x,
                                                      const float* __restrict__ lnsc,
                                                      unsigned short* __restrict__ y,
                                                      float* __restrict__ ssq,
                                                      const float* __restrict__ wqkv,
                                                      const float* __restrict__ wout,
                                                      unsigned short* __restrict__ wqkvt,
                                                      unsigned short* __restrict__ woutt) {
    const int t = threadIdx.x;
    if (blockIdx.x >= 2048) {
        const int i = (blockIdx.x - 2048) * 256 + t;
        if (i < 512 * 1536) {
            int f = i >> 9, c = i & 511;
            wqkvt[i] = f2bf(wqkv[(size_t)c * 1536 + f]);
        } else {
            int j = i - 512 * 1536;
            int n = j >> 9, k = j & 511;
            woutt[j] = f2bf(wout[(size_t)k * 512 + n]);
        }
        return;
    }
    if (blockIdx.x < 32) ssq[(blockIdx.x << 8) | t] = 0.0f;  // zero norm accumulators
    const int token = blockIdx.x * 4 + (t >> 6);
    const int lane = t & 63;
    const float4* xp = (const float4*)(x + (size_t)token * 512 + lane * 8);
    float4 v0 = xp[0], v1 = xp[1];
    float s = v0.x + v0.y + v0.z + v0.w + v1.x + v1.y + v1.z + v1.w;
    float s2 = v0.x * v0.x + v0.y * v0.y + v0.z * v0.z + v0.w * v0.w +
               v1.x * v1.x + v1.y * v1.y + v1.z * v1.z + v1.w * v1.w;
#pragma unroll
    for (int off = 1; off < 64; off <<= 1) {
        s += __shfl_xor(s, off);
        s2 += __shfl_xor(s2, off);
    }
    const float mean = s * (1.0f / 512.0f);
    const float var = s2 * (1.0f / 512.0f) - mean * mean;
    const float rstd = rsqrtf(var + 1e-5f);
    const float4* sp = (const float4*)(lnsc + lane * 8);
    float4 sc0 = sp[0], sc1 = sp[1];
    union { __bf16 h[8]; uint4 v; } pk;
    pk.h[0] = (__bf16)((v0.x - mean) * rstd * sc0.x);
    pk.h[1] = (__bf16)((v0.y - mean) * rstd * sc0.y);
    pk.h[2] = (__bf16)((v0.z - mean) * rstd * sc0.z);
    pk.h[3] = (__bf16)((v0.w - mean) * rstd * sc0.w);
    pk.h[4] = (__bf16)((v1.x - mean) * rstd * sc1.x);
    pk.h[5] = (__bf16)((v1.y - mean) * rstd * sc1.y);
    pk.h[6] = (__bf16)((v1.z - mean) * rstd * sc1.z);
    pk.h[7] = (__bf16)((v1.w - mean) * rstd * sc1.w);
    *(uint4*)(y + (size_t)token * 512 + lane * 8) = pk.v;
}

// ------------------------------------------------------- GEMM C = A * Bt^T
// A: [M,K] bf16 row-major, Bt: [N,K] bf16 row-major. Block tile 2WM x 2WN,
// BK=64, 4 waves (2x2). XOR-swizzled LDS via pre-swizzled global source.
// SSQ: accumulate per-column sum-of-squares (cols < 1024) for l2norm folding.
// VT: for bC>=8 (V columns), transpose tile in LDS and write vt[bh][d][n]
//     instead of writing into qkv.
template <int WM, int WN, int NCOLS, bool OUT_BF16, bool BIAS, bool SSQ, bool VT>
__global__ __launch_bounds__(256) void gemm_bt(const unsigned short* __restrict__ A,
                                               const unsigned short* __restrict__ Bt,
                                               void* __restrict__ Cout,
                                               const float* __restrict__ bias,
                                               float* __restrict__ ssq,
                                               unsigned short* __restrict__ vt,
                                               int M, int K) {
    constexpr int BM = 2 * WM, BN = 2 * WN;
    constexpr int AB_BYTES = (BM + BN) * 64 * 2;
    constexpr int TT_BYTES = 128 * 136 * 2;  // padded transpose tile (stride 136)
    constexpr int LDS_BYTES = (VT && TT_BYTES > AB_BYTES) ? TT_BYTES : AB_BYTES;
    __shared__ __align__(16) char smem[LDS_BYTES];
    unsigned short* As = (unsigned short*)smem;
    unsigned short* Bs = (unsigned short*)(smem + (size_t)BM * 64 * 2);
    const int t = threadIdx.x;
    const int w = t >> 6, lane = t & 63;
    const int g = lane >> 4, l15 = lane & 15;
    const int wr = w >> 1, wc = w & 1;
    const int bR = blockIdx.y, bC = blockIdx.x;
    f32x4 acc[WM / 16][WN / 16] = {};
    const size_t ldb = (size_t)K * 2;
    const char* Ag = (const char*)A + (size_t)bR * BM * ldb;
    const char* Bg = (const char*)Bt + (size_t)bC * BN * ldb;

    for (int kt = 0; kt < K; kt += 64) {
        __syncthreads();
#pragma unroll
        for (int i = 0; i < WM / 16; i++) {
            int o = i * 4096 + t * 16;
            int row = o >> 7, kb = (o & 127) ^ ((row & 7) << 4);
            GLOAD16(Ag + (size_t)row * ldb + (size_t)kt * 2 + kb, (char*)As + o);
        }
#pragma unroll
        for (int i = 0; i < WN / 16; i++) {
            int o = i * 4096 + t * 16;
            int row = o >> 7, kb = (o & 127) ^ ((row & 7) << 4);
            GLOAD16(Bg + (size_t)row * ldb + (size_t)kt * 2 + kb, (char*)Bs + o);
        }
        asm volatile("s_waitcnt vmcnt(0)" ::: "memory");
        __syncthreads();
#pragma unroll
        for (int kk = 0; kk < 64; kk += 32) {
            bf16x8 a[WM / 16], bb[WN / 16];
#pragma unroll
            for (int m = 0; m < WM / 16; m++) {
                int row = wr * WM + m * 16 + l15;
                int kb = ((kk + g * 8) * 2) ^ ((row & 7) << 4);
                a[m] = *(const bf16x8*)((const char*)As + row * 128 + kb);
            }
#pragma unroll
            for (int n = 0; n < WN / 16; n++) {
                int row = wc * WN + n * 16 + l15;
                int kb = ((kk + g * 8) * 2) ^ ((row & 7) << 4);
                bb[n] = *(const bf16x8*)((const char*)Bs + row * 128 + kb);
            }
#pragma unroll
            for (int m = 0; m < WM / 16; m++)
#pragma unroll
                for (int n = 0; n < WN / 16; n++)
                    acc[m][n] = mfma16(a[m], bb[n], acc[m][n]);
        }
    }
    const int rbase = bR * BM + wr * WM;
    const int cbase = bC * BN + wc * WN;
    if (!VT || bC < 8) {
#pragma unroll
        for (int m = 0; m < WM / 16; m++)
#pragma unroll
            for (int n = 0; n < WN / 16; n++)
#pragma unroll
                for (int r = 0; r < 4; r++) {
                    int row = rbase + m * 16 + g * 4 + r;
                    int col = cbase + n * 16 + l15;
                    float v = acc[m][n][r];
                    if constexpr (OUT_BF16)
                        ((unsigned short*)Cout)[(size_t)row * NCOLS + col] = f2bf(v);
                    else
                        ((float*)Cout)[(size_t)row * NCOLS + col] =
                            v + (BIAS ? bias[col] : 0.f);
                }
    }
    if constexpr (SSQ) {
        if (bC < 8) {  // q,k columns only (cols < 1024)
            const int bb2 = bR >> 3;
#pragma unroll
            for (int n = 0; n < WN / 16; n++) {
                float ps = 0.f;
#pragma unroll
                for (int m = 0; m < WM / 16; m++)
#pragma unroll
                    for (int r = 0; r < 4; r++) ps += acc[m][n][r] * acc[m][n][r];
                ps += __shfl_xor(ps, 16);
                ps += __shfl_xor(ps, 32);
                if (g == 0)
                    atomicAdd(&ssq[bb2 * 1024 + cbase + n * 16 + l15], ps);
            }
        }
    }
    if constexpr (VT) {
        if (bC >= 8) {
            unsigned short* TT = (unsigned short*)smem;
            __syncthreads();  // K-loop LDS reads done before overwrite
#pragma unroll
            for (int m = 0; m < WM / 16; m++)
#pragma unroll
                for (int n = 0; n < WN / 16; n++)
#pragma unroll
                    for (int r = 0; r < 4; r++) {
                        int row = wr * WM + m * 16 + g * 4 + r;  // token-local
                        int col = wc * WN + n * 16 + l15;        // f-local
                        TT[col * 136 + row] = f2bf(acc[m][n][r]);
                    }
            __syncthreads();
            const int f = t >> 1, th = t & 1;
            const int fh = (bC - 8) * 128 + f;
            const int hh = fh >> 6, dd = fh & 63;
            const int bb3 = bR >> 3, nb = (bR & 7) * 128;
            unsigned short* dst =
                vt + (((size_t)bb3 * 8 + hh) * 64 + dd) * 1024 + nb + th * 64;
            const unsigned short* srcp = TT + f * 136 + th * 64;
#pragma unroll
            for (int j = 0; j < 8; j++)
                *(uint4*)(dst + j * 8) = *(const uint4*)(srcp + j * 8);
        }
    }
}

// ------------------------------------------------------- flash-ish attention
// grid: x = q-tile of 128 (8 per batch), y = bh (64). 4 waves, each 32 q-rows.
// Q in registers, scaled at load by sm[d]=10*log2e/(|q_d||k_d|) from ssq.
// K raw; KVBLK=64, dbuf K/V staged via global_load_lds, counted vmcnt.
// Swapped QK^T (mfma(K,Q)) -> lane owns P row slice -> pack -> LDS P.
__global__ __launch_bounds__(256) void attn_kernel(const unsigned short* __restrict__ qkv,
                                                   const unsigned short* __restrict__ vt,
                                                   unsigned short* __restrict__ attnout,
                                                   const float* __restrict__ ssq) {
    __shared__ unsigned short Ks[2][4096];
    __shared__ unsigned short Vs[2][4096];
    __shared__ unsigned short Ps[4][2048];  // per wave: 32 q x 64 kv, swizzled
    __shared__ float smq[64];
    const int t = threadIdx.x, w = t >> 6, lane = t & 63;
    const int g = lane >> 4, l15 = lane & 15;
    const int qt = blockIdx.x, bh = blockIdx.y;
    const int b = bh >> 3, h = bh & 7;
    const size_t qrow0 = (size_t)b * 1024 + qt * 128;
    const char* qg = (const char*)qkv;
    const char* vg = (const char*)vt;

    if (t < 64) {
        float nq = fmaxf(sqrtf(ssq[b * 1024 + h * 64 + t]), 1e-12f);
        float nk = fmaxf(sqrtf(ssq[b * 1024 + 512 + h * 64 + t]), 1e-12f);
        smq[t] = 14.42695040888963f / (nq * nk);  // 10*log2(e) folded in
    }
    __syncthreads();

    // Q fragments in registers, scaled: row = qrow0+w*32+qb*16+l15, d = c*32+g*8+j
    bf16x8 qf[2][2];
#pragma unroll
    for (int qb = 0; qb < 2; qb++)
#pragma unroll
        for (int c = 0; c < 2; c++) {
            union { bf16x8 v; unsigned short u[8]; } in, ov;
            in.v = *(const bf16x8*)(qkv + (qrow0 + w * 32 + qb * 16 + l15) * 1536 +
                                    h * 64 + c * 32 + g * 8);
#pragma unroll
            for (int j = 0; j < 8; j++)
                ov.u[j] = f2bf(bf2f(in.u[j]) * smq[c * 32 + g * 8 + j]);
            qf[qb][c] = ov.v;
        }

    f32x4 accO[2][4] = {};
    float prs[2] = {0.f, 0.f};

#define ASTAGE(buf, tt_)                                                              \
    {                                                                                 \
        const int kt_ = (tt_) * 64;                                                   \
        _Pragma("unroll") for (int i = 0; i < 2; i++) {                               \
            int o = i * 4096 + t * 16;                                                \
            int row = o >> 7, kb = (o & 127) ^ ((row & 7) << 4);                      \
            GLOAD16(qg + ((size_t)b * 1024 + kt_ + row) * 3072 + 1024 + h * 128 + kb, \
                    (char*)Ks[buf] + o);                                              \
            GLOAD16(vg + ((size_t)bh * 64 + row) * 2048 + (size_t)kt_ * 2 + kb,       \
                    (char*)Vs[buf] + o);                                              \
        }                                                                             \
    }

    ASTAGE(0, 0)
    for (int tt = 0; tt < 16; ++tt) {
        const int cur = tt & 1;
        if (tt < 15) {
            ASTAGE(cur ^ 1, tt + 1)
            asm volatile("s_waitcnt vmcnt(4)" ::: "memory");
        } else {
            asm volatile("s_waitcnt vmcnt(0)" ::: "memory");
        }
        __builtin_amdgcn_s_barrier();

        // S^T = K Q^T : s[qb][n], lane holds q=l15, kv = n*16 + g*4 + r
        f32x4 s[2][4] = {};
        __builtin_amdgcn_s_setprio(1);
#pragma unroll
        for (int c = 0; c < 2; c++) {
            bf16x8 bk[4];
#pragma unroll
            for (int n = 0; n < 4; n++) {
                int krow = n * 16 + l15;
                int kb = ((c * 32 + g * 8) * 2) ^ ((krow & 7) << 4);
                bk[n] = *(const bf16x8*)((const char*)Ks[cur] + krow * 128 + kb);
            }
#pragma unroll
            for (int qb = 0; qb < 2; qb++)
#pragma unroll
                for (int n = 0; n < 4; n++)
                    s[qb][n] = mfma16(bk[n], qf[qb][c], s[qb][n]);
        }
        __builtin_amdgcn_s_setprio(0);
        // P = 2^s ; rowsum; pack pairs -> Ps (XOR-swizzled, conflict-free b64)
#pragma unroll
        for (int qb = 0; qb < 2; qb++) {
            const int prow = qb * 16 + l15;
#pragma unroll
            for (int n = 0; n < 4; n++) {
                float p0 = __builtin_amdgcn_exp2f(s[qb][n][0]);
                float p1 = __builtin_amdgcn_exp2f(s[qb][n][1]);
                float p2 = __builtin_amdgcn_exp2f(s[qb][n][2]);
                float p3 = __builtin_amdgcn_exp2f(s[qb][n][3]);
                prs[qb] += (p0 + p1) + (p2 + p3);
                uint2 pk;
                pk.x = packbf2(p0, p1);
                pk.y = packbf2(p2, p3);
                int kb = ((n * 16 + g * 4) * 2) ^ ((prow & 7) << 4);
                *(uint2*)((char*)Ps[w] + prow * 128 + kb) = pk;
            }
        }
        // O += P * V  (A = P [q x kv], B = Vt [d x kv])
        __builtin_amdgcn_s_setprio(1);
#pragma unroll
        for (int c2 = 0; c2 < 2; c2++) {
            bf16x8 bv[4];
#pragma unroll
            for (int n = 0; n < 4; n++) {
                int vrow = n * 16 + l15;
                int kb = ((c2 * 32 + g * 8) * 2) ^ ((vrow & 7) << 4);
                bv[n] = *(const bf16x8*)((const char*)Vs[cur] + vrow * 128 + kb);
            }
#pragma unroll
            for (int qb = 0; qb < 2; qb++) {
                const int prow = qb * 16 + l15;
                int kb = ((c2 * 32 + g * 8) * 2) ^ ((prow & 7) << 4);
                bf16x8 ap = *(const bf16x8*)((const char*)Ps[w] + prow * 128 + kb);
#pragma unroll
                for (int n = 0; n < 4; n++)
                    accO[qb][n] = mfma16(ap, bv[n], accO[qb][n]);
            }
        }
        __builtin_amdgcn_s_setprio(0);
        __builtin_amdgcn_s_barrier();
    }
#undef ASTAGE
    // epilogue: rowsum reduce over g, redistribute, divide, store bf16
#pragma unroll
    for (int qb = 0; qb < 2; qb++) {
        float tot = prs[qb];
        tot += __shfl_xor(tot, 16);
        tot += __shfl_xor(tot, 32);
        float inv[4];
#pragma unroll
        for (int r = 0; r < 4; r++) inv[r] = 1.0f / __shfl(tot, g * 4 + r);
#pragma unroll
        for (int n = 0; n < 4; n++)
#pragma unroll
            for (int r = 0; r < 4; r++)
                attnout[(qrow0 + w * 32 + qb * 16 + g * 4 + r) * 512 + h * 64 + n * 16 +
                        l15] = f2bf(accO[qb][n][r] * inv[r]);
    }
}

// ---------------------------------------------------------------- launcher
extern "C" void kernel_launch(void* const* d_in, const int* in_sizes, int n_in,
                              void* d_out, int out_size, void* d_ws, size_t ws_size,
                              hipStream_t stream) {
    const float* x = (const float*)d_in[0];
    const float* ln_scale = (const float*)d_in[1];
    const float* w_qkv = (const float*)d_in[2];
    const float* w_out = (const float*)d_in[3];
    const float* b_out = (const float*)d_in[4];
    float* out = (float*)d_out;

    char* ws = (char*)d_ws;
    unsigned short* y = (unsigned short*)(ws + 0);            // 8 MB (reused as attnout)
    unsigned short* wqkvt = (unsigned short*)(ws + 8388608);  // 1.5 MB
    unsigned short* woutt = (unsigned short*)(ws + 9961472);  // 0.5 MB
    unsigned short* qkv = (unsigned short*)(ws + 10485760);   // 24 MB (V slice unused)
    unsigned short* vt = (unsigned short*)(ws + 35651584);    // 8 MB
    float* ssq = (float*)(ws + 44040192);                     // 32 KB
    unsigned short* attnout = (unsigned short*)(ws + 0);      // overlaps y (dead)

    ln_conv_kernel<<<6144, 256, 0, stream>>>(x, ln_scale, y, ssq, w_qkv, w_out, wqkvt,
                                             woutt);
    gemm_bt<64, 64, 1536, true, false, true, true><<<dim3(12, 64), 256, 0, stream>>>(
        y, wqkvt, qkv, nullptr, ssq, vt, 8192, 512);
    attn_kernel<<<dim3(8, 64), 256, 0, stream>>>(qkv, vt, attnout, ssq);
    gemm_bt<32, 64, 512, false, true, false, false><<<dim3(4, 128), 256, 0, stream>>>(
        attnout, woutt, out, b_out, nullptr, nullptr, 8192, 512);
}

// Round 4
// 78.224 us; speedup vs baseline: 1.6183x; 1.0423x over previous
//
#include <hip/hip_runtime.h>

typedef __bf16 bf16x8 __attribute__((ext_vector_type(8)));
typedef float f32x4 __attribute__((ext_vector_type(4)));

#define DEV static __device__ __forceinline__

DEV unsigned short f2bf(float f) {
    union { __bf16 h; unsigned short s; } c; c.h = (__bf16)f; return c.s;
}
DEV float bf2f(unsigned short h) {
    union { unsigned u; float f; } c; c.u = ((unsigned)h) << 16; return c.f;
}
DEV unsigned packbf2(float a, float b) {
    union { __bf16 h[2]; unsigned u; } c;
    c.h[0] = (__bf16)a; c.h[1] = (__bf16)b; return c.u;
}

DEV f32x4 mfma16(bf16x8 a, bf16x8 b, f32x4 c) {
    return __builtin_amdgcn_mfma_f32_16x16x32_bf16(a, b, c, 0, 0, 0);
}

#define GLOAD16(gp, lp)                                                        \
    __builtin_amdgcn_global_load_lds(                                          \
        (const __attribute__((address_space(1))) unsigned int*)(gp),           \
        (__attribute__((address_space(3))) unsigned int*)(lp), 16, 0, 0)

// --------------------- LN -> y bf16 (blocks < 2048) + weight transpose tiles
__global__ __launch_bounds__(256) void ln_conv_kernel(const float* __restrict__ x,
                                                      const float* __restrict__ lnsc,
                                                      unsigned short* __restrict__ y,
                                                      float* __restrict__ ssq,
                                                      const float* __restrict__ wqkv,
                                                      const float* __restrict__ wout,
                                                      unsigned short* __restrict__ wqkvt,
                                                      unsigned short* __restrict__ woutt) {
    const int t = threadIdx.x;
    if (blockIdx.x >= 2048) {
        // 64x64 LDS tile transpose, fp32 -> bf16, coalesced both sides.
        __shared__ __bf16 tile[64][65];
        const int wblk = blockIdx.x - 2048;
        const float* src;
        unsigned short* dst;
        int ldsrc, k0, f0;
        if (wblk < 192) {  // w_qkv [512,1536] -> wqkvt [1536,512]
            src = wqkv; dst = wqkvt; ldsrc = 1536;
            k0 = (wblk / 24) * 64; f0 = (wblk % 24) * 64;
        } else {           // w_out [512,512] -> woutt [512,512]
            int w2 = wblk - 192;
            src = wout; dst = woutt; ldsrc = 512;
            k0 = (w2 >> 3) * 64; f0 = (w2 & 7) * 64;
        }
#pragma unroll
        for (int j = 0; j < 16; j++) {
            int idx = t + j * 256;
            int a = idx >> 6, b2 = idx & 63;
            tile[b2][a] = (__bf16)src[(size_t)(k0 + a) * ldsrc + f0 + b2];
        }
        __syncthreads();
#pragma unroll
        for (int j = 0; j < 16; j++) {
            int idx = t + j * 256;
            int fb = idx >> 6, kc = idx & 63;
            union { __bf16 h; unsigned short s; } cv;
            cv.h = tile[fb][kc];
            dst[(size_t)(f0 + fb) * 512 + k0 + kc] = cv.s;
        }
        return;
    }
    if (blockIdx.x < 32) ssq[(blockIdx.x << 8) | t] = 0.0f;  // zero norm accumulators
    const int token = blockIdx.x * 4 + (t >> 6);
    const int lane = t & 63;
    const float4* xp = (const float4*)(x + (size_t)token * 512 + lane * 8);
    float4 v0 = xp[0], v1 = xp[1];
    float s = v0.x + v0.y + v0.z + v0.w + v1.x + v1.y + v1.z + v1.w;
    float s2 = v0.x * v0.x + v0.y * v0.y + v0.z * v0.z + v0.w * v0.w +
               v1.x * v1.x + v1.y * v1.y + v1.z * v1.z + v1.w * v1.w;
#pragma unroll
    for (int off = 1; off < 64; off <<= 1) {
        s += __shfl_xor(s, off);
        s2 += __shfl_xor(s2, off);
    }
    const float mean = s * (1.0f / 512.0f);
    const float var = s2 * (1.0f / 512.0f) - mean * mean;
    const float rstd = rsqrtf(var + 1e-5f);
    const float4* sp = (const float4*)(lnsc + lane * 8);
    float4 sc0 = sp[0], sc1 = sp[1];
    union { __bf16 h[8]; uint4 v; } pk;
    pk.h[0] = (__bf16)((v0.x - mean) * rstd * sc0.x);
    pk.h[1] = (__bf16)((v0.y - mean) * rstd * sc0.y);
    pk.h[2] = (__bf16)((v0.z - mean) * rstd * sc0.z);
    pk.h[3] = (__bf16)((v0.w - mean) * rstd * sc0.w);
    pk.h[4] = (__bf16)((v1.x - mean) * rstd * sc1.x);
    pk.h[5] = (__bf16)((v1.y - mean) * rstd * sc1.y);
    pk.h[6] = (__bf16)((v1.z - mean) * rstd * sc1.z);
    pk.h[7] = (__bf16)((v1.w - mean) * rstd * sc1.w);
    *(uint4*)(y + (size_t)token * 512 + lane * 8) = pk.v;
}

// ------------------------------------------------------- GEMM C = A * Bt^T
// A: [M,K] bf16 row-major, Bt: [N,K] bf16 row-major. Block tile 2WM x 2WN,
// BK=64, 4 waves (2x2). Double-buffered LDS, stage-ahead + counted vmcnt
// (T3-minimum). XOR-swizzled LDS via pre-swizzled global source.
// SSQ: accumulate per-column sum-of-squares (cols < 1024) for l2norm folding.
// VT: for bC>=8 (V columns), transpose tile in LDS and write vt[bh][d][n].
template <int WM, int WN, int NCOLS, bool OUT_BF16, bool BIAS, bool SSQ, bool VT>
__global__ __launch_bounds__(256) void gemm_bt(const unsigned short* __restrict__ A,
                                               const unsigned short* __restrict__ Bt,
                                               void* __restrict__ Cout,
                                               const float* __restrict__ bias,
                                               float* __restrict__ ssq,
                                               unsigned short* __restrict__ vt,
                                               int M, int K) {
    constexpr int BM = 2 * WM, BN = 2 * WN;
    constexpr int ASZ = BM * 64 * 2, BSZ = BN * 64 * 2;
    constexpr int NLA = WM / 16, NLB = WN / 16;  // gloads per thread per stage
    constexpr int DBUF = 2 * (ASZ + BSZ);
    constexpr int TTB = VT ? 128 * 136 * 2 : 0;
    constexpr int LDSB = DBUF > TTB ? DBUF : TTB;
    __shared__ __align__(16) char smem[LDSB];
    const int t = threadIdx.x;
    const int w = t >> 6, lane = t & 63;
    const int g = lane >> 4, l15 = lane & 15;
    const int wr = w >> 1, wc = w & 1;
    const int bR = blockIdx.y, bC = blockIdx.x;
    f32x4 acc[NLA][NLB] = {};
    const size_t ldb = (size_t)K * 2;
    const char* Ag = (const char*)A + (size_t)bR * BM * ldb;
    const char* Bg = (const char*)Bt + (size_t)bC * BN * ldb;

#define GSTAGE(buf, kt_)                                                            \
    {                                                                               \
        char* Ad = smem + (buf) * (ASZ + BSZ);                                      \
        char* Bd = Ad + ASZ;                                                        \
        _Pragma("unroll") for (int i = 0; i < NLA; i++) {                           \
            int o = i * 4096 + t * 16;                                              \
            int row = o >> 7, kb = (o & 127) ^ ((row & 7) << 4);                    \
            GLOAD16(Ag + (size_t)row * ldb + (size_t)(kt_) * 2 + kb, Ad + o);       \
        }                                                                           \
        _Pragma("unroll") for (int i = 0; i < NLB; i++) {                           \
            int o = i * 4096 + t * 16;                                              \
            int row = o >> 7, kb = (o & 127) ^ ((row & 7) << 4);                    \
            GLOAD16(Bg + (size_t)row * ldb + (size_t)(kt_) * 2 + kb, Bd + o);       \
        }                                                                           \
    }

    GSTAGE(0, 0)
    const int NT = K >> 6;
    for (int tt = 0; tt < NT; ++tt) {
        const int cur = tt & 1;
        if (tt + 1 < NT) {
            GSTAGE(cur ^ 1, (tt + 1) * 64)
            asm volatile("s_waitcnt vmcnt(%0)" ::"n"(NLA + NLB) : "memory");
        } else {
            asm volatile("s_waitcnt vmcnt(0)" ::: "memory");
        }
        __builtin_amdgcn_s_barrier();
        const char* Ab = smem + cur * (ASZ + BSZ);
        const char* Bb = Ab + ASZ;
#pragma unroll
        for (int kk = 0; kk < 64; kk += 32) {
            bf16x8 a[NLA], bb[NLB];
#pragma unroll
            for (int m = 0; m < NLA; m++) {
                int row = wr * WM + m * 16 + l15;
                int kb = ((kk + g * 8) * 2) ^ ((row & 7) << 4);
                a[m] = *(const bf16x8*)(Ab + row * 128 + kb);
            }
#pragma unroll
            for (int n = 0; n < NLB; n++) {
                int row = wc * WN + n * 16 + l15;
                int kb = ((kk + g * 8) * 2) ^ ((row & 7) << 4);
                bb[n] = *(const bf16x8*)(Bb + row * 128 + kb);
            }
#pragma unroll
            for (int m = 0; m < NLA; m++)
#pragma unroll
                for (int n = 0; n < NLB; n++)
                    acc[m][n] = mfma16(a[m], bb[n], acc[m][n]);
        }
        __builtin_amdgcn_s_barrier();
    }
#undef GSTAGE

    const int rbase = bR * BM + wr * WM;
    const int cbase = bC * BN + wc * WN;
    if (!VT || bC < 8) {
#pragma unroll
        for (int m = 0; m < NLA; m++)
#pragma unroll
            for (int n = 0; n < NLB; n++)
#pragma unroll
                for (int r = 0; r < 4; r++) {
                    int row = rbase + m * 16 + g * 4 + r;
                    int col = cbase + n * 16 + l15;
                    float v = acc[m][n][r];
                    if constexpr (OUT_BF16)
                        ((unsigned short*)Cout)[(size_t)row * NCOLS + col] = f2bf(v);
                    else
                        ((float*)Cout)[(size_t)row * NCOLS + col] =
                            v + (BIAS ? bias[col] : 0.f);
                }
    }
    if constexpr (SSQ) {
        if (bC < 8) {  // q,k columns only (cols < 1024)
            const int bb2 = bR >> 3;
#pragma unroll
            for (int n = 0; n < NLB; n++) {
                float ps = 0.f;
#pragma unroll
                for (int m = 0; m < NLA; m++)
#pragma unroll
                    for (int r = 0; r < 4; r++) ps += acc[m][n][r] * acc[m][n][r];
                ps += __shfl_xor(ps, 16);
                ps += __shfl_xor(ps, 32);
                if (g == 0)
                    atomicAdd(&ssq[bb2 * 1024 + cbase + n * 16 + l15], ps);
            }
        }
    }
    if constexpr (VT) {
        if (bC >= 8) {
            unsigned short* TT = (unsigned short*)smem;
            __syncthreads();  // all K-loop LDS reads done before overwrite
#pragma unroll
            for (int m = 0; m < NLA; m++)
#pragma unroll
                for (int n = 0; n < NLB; n++)
#pragma unroll
                    for (int r = 0; r < 4; r++) {
                        int row = wr * WM + m * 16 + g * 4 + r;  // token-local
                        int col = wc * WN + n * 16 + l15;        // f-local
                        TT[col * 136 + row] = f2bf(acc[m][n][r]);
                    }
            __syncthreads();
            const int f = t >> 1, th = t & 1;
            const int fh = (bC - 8) * 128 + f;
            const int hh = fh >> 6, dd = fh & 63;
            const int bb3 = bR >> 3, nb = (bR & 7) * 128;
            unsigned short* dst =
                vt + (((size_t)bb3 * 8 + hh) * 64 + dd) * 1024 + nb + th * 64;
            const unsigned short* srcp = TT + f * 136 + th * 64;
#pragma unroll
            for (int j = 0; j < 8; j++)
                *(uint4*)(dst + j * 8) = *(const uint4*)(srcp + j * 8);
        }
    }
}

// ------------------------------------------------------- flash-ish attention
// grid: x = q-tile of 128 (8 per batch), y = bh (64). 4 waves, each 32 q-rows.
// Q in registers, scaled at load by sm[d]=10*log2e/(|q_d||k_d|) from ssq.
// K raw; KVBLK=64, dbuf K/V staged via global_load_lds, counted vmcnt.
// Swapped QK^T (mfma(K,Q)) -> lane owns P row slice -> pack -> LDS P.
__global__ __launch_bounds__(256) void attn_kernel(const unsigned short* __restrict__ qkv,
                                                   const unsigned short* __restrict__ vt,
                                                   unsigned short* __restrict__ attnout,
                                                   const float* __restrict__ ssq) {
    __shared__ unsigned short Ks[2][4096];
    __shared__ unsigned short Vs[2][4096];
    __shared__ unsigned short Ps[4][2048];  // per wave: 32 q x 64 kv, swizzled
    __shared__ float smq[64];
    const int t = threadIdx.x, w = t >> 6, lane = t & 63;
    const int g = lane >> 4, l15 = lane & 15;
    const int qt = blockIdx.x, bh = blockIdx.y;
    const int b = bh >> 3, h = bh & 7;
    const size_t qrow0 = (size_t)b * 1024 + qt * 128;
    const char* qg = (const char*)qkv;
    const char* vg = (const char*)vt;

    if (t < 64) {
        float nq = fmaxf(sqrtf(ssq[b * 1024 + h * 64 + t]), 1e-12f);
        float nk = fmaxf(sqrtf(ssq[b * 1024 + 512 + h * 64 + t]), 1e-12f);
        smq[t] = 14.42695040888963f / (nq * nk);  // 10*log2(e) folded in
    }
    __syncthreads();

    // Q fragments in registers, scaled: row = qrow0+w*32+qb*16+l15, d = c*32+g*8+j
    bf16x8 qf[2][2];
#pragma unroll
    for (int qb = 0; qb < 2; qb++)
#pragma unroll
        for (int c = 0; c < 2; c++) {
            union { bf16x8 v; unsigned short u[8]; } in, ov;
            in.v = *(const bf16x8*)(qkv + (qrow0 + w * 32 + qb * 16 + l15) * 1536 +
                                    h * 64 + c * 32 + g * 8);
#pragma unroll
            for (int j = 0; j < 8; j++)
                ov.u[j] = f2bf(bf2f(in.u[j]) * smq[c * 32 + g * 8 + j]);
            qf[qb][c] = ov.v;
        }

    f32x4 accO[2][4] = {};
    float prs[2] = {0.f, 0.f};

#define ASTAGE(buf, tt_)                                                              \
    {                                                                                 \
        const int kt_ = (tt_) * 64;                                                   \
        _Pragma("unroll") for (int i = 0; i < 2; i++) {                               \
            int o = i * 4096 + t * 16;                                                \
            int row = o >> 7, kb = (o & 127) ^ ((row & 7) << 4);                      \
            GLOAD16(qg + ((size_t)b * 1024 + kt_ + row) * 3072 + 1024 + h * 128 + kb, \
                    (char*)Ks[buf] + o);                                              \
            GLOAD16(vg + ((size_t)bh * 64 + row) * 2048 + (size_t)kt_ * 2 + kb,       \
                    (char*)Vs[buf] + o);                                              \
        }                                                                             \
    }

    ASTAGE(0, 0)
    for (int tt = 0; tt < 16; ++tt) {
        const int cur = tt & 1;
        if (tt < 15) {
            ASTAGE(cur ^ 1, tt + 1)
            asm volatile("s_waitcnt vmcnt(4)" ::: "memory");
        } else {
            asm volatile("s_waitcnt vmcnt(0)" ::: "memory");
        }
        __builtin_amdgcn_s_barrier();

        // S^T = K Q^T : s[qb][n], lane holds q=l15, kv = n*16 + g*4 + r
        f32x4 s[2][4] = {};
        __builtin_amdgcn_s_setprio(1);
#pragma unroll
        for (int c = 0; c < 2; c++) {
            bf16x8 bk[4];
#pragma unroll
            for (int n = 0; n < 4; n++) {
                int krow = n * 16 + l15;
                int kb = ((c * 32 + g * 8) * 2) ^ ((krow & 7) << 4);
                bk[n] = *(const bf16x8*)((const char*)Ks[cur] + krow * 128 + kb);
            }
#pragma unroll
            for (int qb = 0; qb < 2; qb++)
#pragma unroll
                for (int n = 0; n < 4; n++)
                    s[qb][n] = mfma16(bk[n], qf[qb][c], s[qb][n]);
        }
        __builtin_amdgcn_s_setprio(0);
        // P = 2^s ; rowsum; pack pairs -> Ps (XOR-swizzled, conflict-free b64)
#pragma unroll
        for (int qb = 0; qb < 2; qb++) {
            const int prow = qb * 16 + l15;
#pragma unroll
            for (int n = 0; n < 4; n++) {
                float p0 = __builtin_amdgcn_exp2f(s[qb][n][0]);
                float p1 = __builtin_amdgcn_exp2f(s[qb][n][1]);
                float p2 = __builtin_amdgcn_exp2f(s[qb][n][2]);
                float p3 = __builtin_amdgcn_exp2f(s[qb][n][3]);
                prs[qb] += (p0 + p1) + (p2 + p3);
                uint2 pk;
                pk.x = packbf2(p0, p1);
                pk.y = packbf2(p2, p3);
                int kb = ((n * 16 + g * 4) * 2) ^ ((prow & 7) << 4);
                *(uint2*)((char*)Ps[w] + prow * 128 + kb) = pk;
            }
        }
        // O += P * V  (A = P [q x kv], B = Vt [d x kv])
        __builtin_amdgcn_s_setprio(1);
#pragma unroll
        for (int c2 = 0; c2 < 2; c2++) {
            bf16x8 bv[4];
#pragma unroll
            for (int n = 0; n < 4; n++) {
                int vrow = n * 16 + l15;
                int kb = ((c2 * 32 + g * 8) * 2) ^ ((vrow & 7) << 4);
                bv[n] = *(const bf16x8*)((const char*)Vs[cur] + vrow * 128 + kb);
            }
#pragma unroll
            for (int qb = 0; qb < 2; qb++) {
                const int prow = qb * 16 + l15;
                int kb = ((c2 * 32 + g * 8) * 2) ^ ((prow & 7) << 4);
                bf16x8 ap = *(const bf16x8*)((const char*)Ps[w] + prow * 128 + kb);
#pragma unroll
                for (int n = 0; n < 4; n++)
                    accO[qb][n] = mfma16(ap, bv[n], accO[qb][n]);
            }
        }
        __builtin_amdgcn_s_setprio(0);
        __builtin_amdgcn_s_barrier();
    }
#undef ASTAGE
    // epilogue: rowsum reduce over g, redistribute, divide, store bf16
#pragma unroll
    for (int qb = 0; qb < 2; qb++) {
        float tot = prs[qb];
        tot += __shfl_xor(tot, 16);
        tot += __shfl_xor(tot, 32);
        float inv[4];
#pragma unroll
        for (int r = 0; r < 4; r++) inv[r] = 1.0f / __shfl(tot, g * 4 + r);
#pragma unroll
        for (int n = 0; n < 4; n++)
#pragma unroll
            for (int r = 0; r < 4; r++)
                attnout[(qrow0 + w * 32 + qb * 16 + g * 4 + r) * 512 + h * 64 + n * 16 +
                        l15] = f2bf(accO[qb][n][r] * inv[r]);
    }
}

// ---------------------------------------------------------------- launcher
extern "C" void kernel_launch(void* const* d_in, const int* in_sizes, int n_in,
                              void* d_out, int out_size, void* d_ws, size_t ws_size,
                              hipStream_t stream) {
    const float* x = (const float*)d_in[0];
    const float* ln_scale = (const float*)d_in[1];
    const float* w_qkv = (const float*)d_in[2];
    const float* w_out = (const float*)d_in[3];
    const float* b_out = (const float*)d_in[4];
    float* out = (float*)d_out;

    char* ws = (char*)d_ws;
    unsigned short* y = (unsigned short*)(ws + 0);            // 8 MB (reused as attnout)
    unsigned short* wqkvt = (unsigned short*)(ws + 8388608);  // 1.5 MB
    unsigned short* woutt = (unsigned short*)(ws + 9961472);  // 0.5 MB
    unsigned short* qkv = (unsigned short*)(ws + 10485760);   // 24 MB (V slice unused)
    unsigned short* vt = (unsigned short*)(ws + 35651584);    // 8 MB
    float* ssq = (float*)(ws + 44040192);                     // 32 KB
    unsigned short* attnout = (unsigned short*)(ws + 0);      // overlaps y (dead)

    ln_conv_kernel<<<2304, 256, 0, stream>>>(x, ln_scale, y, ssq, w_qkv, w_out, wqkvt,
                                             woutt);
    gemm_bt<64, 64, 1536, true, false, true, true><<<dim3(12, 64), 256, 0, stream>>>(
        y, wqkvt, qkv, nullptr, ssq, vt, 8192, 512);
    attn_kernel<<<dim3(8, 64), 256, 0, stream>>>(qkv, vt, attnout, ssq);
    gemm_bt<32, 64, 512, false, true, false, false><<<dim3(4, 128), 256, 0, stream>>>(
        attnout, woutt, out, b_out, nullptr, nullptr, 8192, 512);
}